// Round 1
// baseline (23281.856 us; speedup 1.0000x reference)
//
#include <hip/hip_runtime.h>

// Farthest point sampling, pointops semantics.
// B=8 batches, n=65536 pts/batch, stride=64 -> m=1024 samples/batch.
// One workgroup per batch; min-dists in registers; coords streamed from L2.

#define FPS_BLOCK  1024
#define FPS_CHUNKS 16          // n / (FPS_BLOCK*4) for n=65536

__global__ void fps_prep(const float* __restrict__ p,
                         float* __restrict__ xs, float* __restrict__ ys,
                         float* __restrict__ zs, int N) {
    int i = blockIdx.x * blockDim.x + threadIdx.x;
    if (i < N) {
        float a = p[3 * i + 0];
        float b = p[3 * i + 1];
        float c = p[3 * i + 2];
        xs[i] = a; ys[i] = b; zs[i] = c;
    }
}

__global__ __launch_bounds__(FPS_BLOCK, 4)
void fps_kernel(const float* __restrict__ p,
                const float* __restrict__ xs, const float* __restrict__ ys,
                const float* __restrict__ zs,
                int use_soa, int n, int m,
                float* __restrict__ out_np, float* __restrict__ out_no,
                float* __restrict__ out_idx) {
#pragma clang fp contract(off)
    const int b = blockIdx.x;
    const int t = threadIdx.x;
    const int gbase = b * n;

    __shared__ float s_val[16];
    __shared__ int   s_idx[16];
    __shared__ float s_q[3];

    // per-thread min-dist registers: point id = (t + k*FPS_BLOCK)*4 + j
    float dist[FPS_CHUNKS * 4];
#pragma unroll
    for (int i = 0; i < FPS_CHUNKS * 4; ++i) dist[i] = 1e10f;

    float qx, qy, qz;
    if (use_soa) {
        qx = xs[gbase]; qy = ys[gbase]; qz = zs[gbase];
    } else {
        qx = p[3 * (size_t)gbase + 0];
        qy = p[3 * (size_t)gbase + 1];
        qz = p[3 * (size_t)gbase + 2];
    }

    if (t == 0) {
        // first sample is local index 0
        out_idx[(size_t)b * m] = (float)gbase;
        out_np[(size_t)(b * m) * 3 + 0] = qx;
        out_np[(size_t)(b * m) * 3 + 1] = qy;
        out_np[(size_t)(b * m) * 3 + 2] = qz;
        out_no[b] = (float)((b + 1) * m);
    }

    for (int it = 1; it < m; ++it) {
        float best = -1.0f;
        int   bidx = 0;

        if (use_soa) {
#pragma unroll
            for (int k = 0; k < FPS_CHUNKS; ++k) {
                int e = gbase + (t + k * FPS_BLOCK) * 4;
                float4 xv = *(const float4*)(xs + e);
                float4 yv = *(const float4*)(ys + e);
                float4 zv = *(const float4*)(zs + e);
                float xl[4] = {xv.x, xv.y, xv.z, xv.w};
                float yl[4] = {yv.x, yv.y, yv.z, yv.w};
                float zl[4] = {zv.x, zv.y, zv.z, zv.w};
#pragma unroll
                for (int j = 0; j < 4; ++j) {
                    float dx = xl[j] - qx;
                    float dy = yl[j] - qy;
                    float dz = zl[j] - qz;
                    float d = dx * dx + dy * dy + dz * dz;  // no contract: left-assoc
                    int li = k * 4 + j;
                    float nd = fminf(dist[li], d);
                    dist[li] = nd;
                    if (nd > best) {  // strictly greater -> keeps earliest (ascending ids per thread)
                        best = nd;
                        bidx = (t + k * FPS_BLOCK) * 4 + j;
                    }
                }
            }
        } else {
#pragma unroll
            for (int k = 0; k < FPS_CHUNKS; ++k) {
#pragma unroll
                for (int j = 0; j < 4; ++j) {
                    int pid = (t + k * FPS_BLOCK) * 4 + j;
                    size_t a3 = 3 * (size_t)(gbase + pid);
                    float dx = p[a3 + 0] - qx;
                    float dy = p[a3 + 1] - qy;
                    float dz = p[a3 + 2] - qz;
                    float d = dx * dx + dy * dy + dz * dz;
                    int li = k * 4 + j;
                    float nd = fminf(dist[li], d);
                    dist[li] = nd;
                    if (nd > best) { best = nd; bidx = pid; }
                }
            }
        }

        // wave-level argmax reduce (64 lanes), tie-break: smaller index
#pragma unroll
        for (int off = 1; off < 64; off <<= 1) {
            float ov = __shfl_xor(best, off);
            int   oi = __shfl_xor(bidx, off);
            if (ov > best || (ov == best && oi < bidx)) { best = ov; bidx = oi; }
        }
        int w = t >> 6;
        if ((t & 63) == 0) { s_val[w] = best; s_idx[w] = bidx; }
        __syncthreads();

        if (t < 64) {
            float v  = (t < 16) ? s_val[t] : -1.0f;
            int   ix = (t < 16) ? s_idx[t] : 0x7fffffff;
#pragma unroll
            for (int off = 1; off < 16; off <<= 1) {
                float ov = __shfl_xor(v, off);
                int   oi = __shfl_xor(ix, off);
                if (ov > v || (ov == v && oi < ix)) { v = ov; ix = oi; }
            }
            if (t == 0) {
                int gi = gbase + ix;
                float nx, ny, nz;
                if (use_soa) {
                    nx = xs[gi]; ny = ys[gi]; nz = zs[gi];
                } else {
                    nx = p[3 * (size_t)gi + 0];
                    ny = p[3 * (size_t)gi + 1];
                    nz = p[3 * (size_t)gi + 2];
                }
                out_idx[(size_t)b * m + it] = (float)gi;
                out_np[(size_t)(b * m + it) * 3 + 0] = nx;
                out_np[(size_t)(b * m + it) * 3 + 1] = ny;
                out_np[(size_t)(b * m + it) * 3 + 2] = nz;
                s_q[0] = nx; s_q[1] = ny; s_q[2] = nz;
            }
        }
        __syncthreads();
        qx = s_q[0]; qy = s_q[1]; qz = s_q[2];
    }
}

extern "C" void kernel_launch(void* const* d_in, const int* in_sizes, int n_in,
                              void* d_out, int out_size, void* d_ws, size_t ws_size,
                              hipStream_t stream) {
    const float* p = (const float*)d_in[0];
    int N = in_sizes[0] / 3;           // 524288
    int B = in_sizes[1];               // 8
    int n = N / B;                     // 65536
    int m = (out_size / B - 1) / 4;    // out_size = B*(4m+1) -> 1024

    float* out_np  = (float*)d_out;
    float* out_no  = out_np + (size_t)B * m * 3;
    float* out_idx = out_no + B;

    int use_soa = 0;
    float *xs = nullptr, *ys = nullptr, *zs = nullptr;
    if (ws_size >= (size_t)N * 3 * sizeof(float)) {
        use_soa = 1;
        xs = (float*)d_ws;
        ys = xs + N;
        zs = ys + N;
        fps_prep<<<(N + 255) / 256, 256, 0, stream>>>(p, xs, ys, zs, N);
    }

    fps_kernel<<<B, FPS_BLOCK, 0, stream>>>(p, xs, ys, zs, use_soa, n, m,
                                            out_np, out_no, out_idx);
}

// Round 2
// 10730.004 us; speedup vs baseline: 2.1698x; 2.1698x over previous
//
#include <hip/hip_runtime.h>
#include <stdint.h>

// Farthest point sampling, pointops semantics.
// B=8 batches, n=65536, stride=64 -> m=1024 samples/batch.
// 32 WGs per batch, coords+dists register-resident, one tagged-slot
// barrier per FPS step (agent-scope atomics, double-buffered by parity).

#define G    32      // workgroups per batch
#define BS   256     // threads per workgroup
#define PPT  8       // points per thread  (G*BS*PPT == n)

typedef unsigned long long u64;
typedef unsigned int u32;

__device__ inline u64 packff(float lo, float hi) {
    return (u64)__float_as_uint(lo) | ((u64)__float_as_uint(hi) << 32);
}
__device__ inline float lowf(u64 v)  { return __uint_as_float((u32)v); }
__device__ inline float highf(u64 v) { return __uint_as_float((u32)(v >> 32)); }

// slot = 4 u64 per (batch, parity, g): [0]=x|y  [1]=z|val  [2]=idx|tag(hi)  [3]=pad
__global__ __launch_bounds__(BS, 1)
void fps_multi(const float* __restrict__ p, int n, int m,
               u64* __restrict__ slots,
               float* __restrict__ out_np, float* __restrict__ out_no,
               float* __restrict__ out_idx)
{
#pragma clang fp contract(off)
    const int bg = blockIdx.x;
    const int b  = bg / G;
    const int g  = bg % G;
    const int t  = threadIdx.x;
    const int gbase  = b * n;          // global point base of this batch
    const int wgbase = g * (BS * PPT); // batch-local base of this WG's points

    __shared__ float s_val[BS / 64];
    __shared__ int   s_idx[BS / 64];
    __shared__ int   s_widx;           // intra-WG winner (batch-local idx)
    __shared__ float s_q[3];
    __shared__ int   s_dummy;

    // ---- load this WG's 2048 points into registers (one-time) ----
    float px[PPT], py[PPT], pz[PPT], dist[PPT];
    {
        const float* base = p + 3ull * (u32)(gbase + wgbase + t * PPT);
#pragma unroll
        for (int j = 0; j < PPT; ++j) {
            px[j] = base[3 * j + 0];
            py[j] = base[3 * j + 1];
            pz[j] = base[3 * j + 2];
            dist[j] = 1e10f;
        }
    }

    // first query = point 0 of the batch
    float qx = p[3ull * (u32)gbase + 0];
    float qy = p[3ull * (u32)gbase + 1];
    float qz = p[3ull * (u32)gbase + 2];

    if (g == 0 && t == 0) {
        out_idx[(size_t)b * m] = (float)gbase;
        out_np[(size_t)(b * m) * 3 + 0] = qx;
        out_np[(size_t)(b * m) * 3 + 1] = qy;
        out_np[(size_t)(b * m) * 3 + 2] = qz;
        out_no[b] = (float)((b + 1) * m);
    }

    for (int it = 1; it < m; ++it) {
        // ---- local distance update + per-thread argmax (ids ascending in j) ----
        float best = -1.0f;
        int   bj   = 0;
#pragma unroll
        for (int j = 0; j < PPT; ++j) {
            float dx = px[j] - qx;
            float dy = py[j] - qy;
            float dz = pz[j] - qz;
            float d  = dx * dx + dy * dy + dz * dz;   // contract off: left-assoc
            float nd = fminf(dist[j], d);
            dist[j] = nd;
            if (nd > best) { best = nd; bj = j; }     // strict > keeps earliest
        }
        int bidx = wgbase + t * PPT + bj;             // batch-local winner idx

        // ---- wave argmax (64 lanes, ids ascend with lane) ----
#pragma unroll
        for (int off = 1; off < 64; off <<= 1) {
            float ov = __shfl_xor(best, off);
            int   oi = __shfl_xor(bidx, off);
            if (ov > best || (ov == best && oi < bidx)) { best = ov; bidx = oi; }
        }
        int w = t >> 6;
        if ((t & 63) == 0) { s_val[w] = best; s_idx[w] = bidx; }
        __syncthreads();

        // ---- cross-wave argmax (4 entries) by thread 0 ----
        if (t == 0) {
            float v = -1.0f; int ix = 0x7fffffff;
#pragma unroll
            for (int ww = 0; ww < BS / 64; ++ww) {
                if (s_val[ww] > v || (s_val[ww] == v && s_idx[ww] < ix)) {
                    v = s_val[ww]; ix = s_idx[ww];
                }
            }
            s_widx = ix;
        }
        __syncthreads();

        // ---- owner thread publishes this WG's candidate slot ----
        {
            int lw = s_widx - wgbase;                 // 0..BS*PPT-1
            if (t == (lw >> 3)) {
                int j = lw & (PPT - 1);
                u64* sl = slots + ((size_t)(b * 2 + (it & 1)) * G + g) * 4;
                __hip_atomic_store(sl + 0, packff(px[j], py[j]),
                                   __ATOMIC_RELAXED, __HIP_MEMORY_SCOPE_AGENT);
                __hip_atomic_store(sl + 1, packff(pz[j], dist[j]),
                                   __ATOMIC_RELAXED, __HIP_MEMORY_SCOPE_AGENT);
                __hip_atomic_store(sl + 2, (u64)(u32)s_widx | ((u64)(u32)it << 32),
                                   __ATOMIC_RELEASE, __HIP_MEMORY_SCOPE_AGENT);
            }
        }

        // ---- wave 0: spin on all G tags, reduce 32 candidates ----
        if (t < 64) {
            u64* sb = slots + (size_t)(b * 2 + (it & 1)) * G * 4;
            u64* sl = sb + (size_t)(t & (G - 1)) * 4;
            u64 c;
            do {
                c = __hip_atomic_load(sl + 2, __ATOMIC_ACQUIRE, __HIP_MEMORY_SCOPE_AGENT);
            } while ((u32)(c >> 32) != (u32)it);
            u64 a  = __hip_atomic_load(sl + 0, __ATOMIC_RELAXED, __HIP_MEMORY_SCOPE_AGENT);
            u64 bb = __hip_atomic_load(sl + 1, __ATOMIC_RELAXED, __HIP_MEMORY_SCOPE_AGENT);
            int   ix = (int)(u32)c;
            float x  = lowf(a),  y = highf(a);
            float z  = lowf(bb), v = highf(bb);
#pragma unroll
            for (int off = 1; off < G; off <<= 1) {
                float ov = __shfl_xor(v, off);
                int   oi = __shfl_xor(ix, off);
                float ox = __shfl_xor(x, off);
                float oy = __shfl_xor(y, off);
                float oz = __shfl_xor(z, off);
                if (ov > v || (ov == v && oi < ix)) {
                    v = ov; ix = oi; x = ox; y = oy; z = oz;
                }
            }
            if (t == 0) {
                s_q[0] = x; s_q[1] = y; s_q[2] = z; s_widx = ix;
                if (g == 0) {
                    out_idx[(size_t)b * m + it] = (float)(gbase + ix);
                    out_np[(size_t)(b * m + it) * 3 + 0] = x;
                    out_np[(size_t)(b * m + it) * 3 + 1] = y;
                    out_np[(size_t)(b * m + it) * 3 + 2] = z;
                }
            }
        }
        __syncthreads();
        qx = s_q[0]; qy = s_q[1]; qz = s_q[2];
    }
    (void)s_dummy;
}

extern "C" void kernel_launch(void* const* d_in, const int* in_sizes, int n_in,
                              void* d_out, int out_size, void* d_ws, size_t ws_size,
                              hipStream_t stream) {
    const float* p = (const float*)d_in[0];
    int N = in_sizes[0] / 3;           // 524288
    int B = in_sizes[1];               // 8
    int n = N / B;                     // 65536
    int m = (out_size / B - 1) / 4;    // 1024

    float* out_np  = (float*)d_out;
    float* out_no  = out_np + (size_t)B * m * 3;
    float* out_idx = out_no + B;

    u64* slots = (u64*)d_ws;
    size_t slot_bytes = (size_t)B * 2 * G * 4 * sizeof(u64);  // 16 KB

    // clear tags every launch (graph-safe) -> no cross-replay staleness
    hipMemsetAsync(d_ws, 0, slot_bytes, stream);

    fps_multi<<<B * G, BS, 0, stream>>>(p, n, m, slots, out_np, out_no, out_idx);
}